// Round 2
// baseline (88.372 us; speedup 1.0000x reference)
//
#include <hip/hip_runtime.h>
#include <cstdint>

// DirectAU loss: align(u,i) + 0.5*(uniform(u) + uniform(i)), T=2, GAMMA=1.
// N=8192 rows, D=64.
//   k1: normalize rows (fp32), pre-scale by sqrt(4*log2(e)), write bf16 copies
//       to ws, per-block align partial. Block 0 zeroes the k2 accumulators.
//   k2: 256x256-tile X@X^T via mfma_f32_16x16x32_bf16. Because inputs are
//       pre-scaled, MFMA output is already the exp2 argument: epilogue is
//       exp2 + accumulate only (diag tiles clamp at e^4; grand total scaled
//       by e^-4 once at the end). cb loop unrolled x2 only — a full unroll
//       could hoist up to 128 B-fragment VGPRs against the 64-VGPR cap from
//       __launch_bounds__(512,8) (spill suspicion from R0 counters).
//       k3 fused in via last-block pattern: per-block partials go to 8-way
//       atomic float slots per matrix + counter; last block reduces pa[] and
//       writes the final scalar. All cross-block traffic is device-scope
//       atomics (no plain-store coherence assumptions, per XCD rules).
// Floor: harness re-poisons the 256 MiB ws with 0xAA every iteration
// (41.4us @ 81% HBM peak, in the timed path) — untouchable.
// R1 note: round-1 bench died in container acquire (no kernel signal).
// Deadlock/fault/capture audit found nothing; resubmitting unchanged.

#define NROWS 8192
#define DIM 64
#define NT2 32                            // 8192/256 tiles per side
#define GRAM_SLOTS (NT2 * (NT2 + 1))      // 32*33 = 1056
#define K1_BLOCKS 512                     // 4 waves/block * 4 rows/wave

// exp(-T*||u-v||^2) = exp(4g-4) = 2^(S*g) * e^-4, S = 4*log2(e).
static constexpr float SQRT_SCALE = 2.4022448309943147f; // sqrt(4*log2(e))
static constexpr float E4        = 54.598150033144236f;  // e^4  (clamp, diag)
static constexpr float E4_INV    = 0.018315638888734179f; // e^-4
static constexpr float EPS_F = 1e-8f;

typedef __bf16 bf16x8 __attribute__((ext_vector_type(8)));
typedef float f32x4 __attribute__((ext_vector_type(4)));

__device__ __forceinline__ unsigned short f32_to_bf16_rn(float f) {
    union { float f; uint32_t u; } c; c.f = f;
    uint32_t u = c.u;
    uint32_t r = u + 0x7FFFu + ((u >> 16) & 1u);
    return (unsigned short)(r >> 16);
}

// ---- kernel 1: normalize + scale + bf16 cast + align partial + acc zero ----
__global__ void __launch_bounds__(256) normalize_align_kernel(
    const float* __restrict__ user, const float* __restrict__ item,
    unsigned short* __restrict__ xu, unsigned short* __restrict__ xi,
    float* __restrict__ pa, float* __restrict__ acc, unsigned* __restrict__ ctr)
{
    if (blockIdx.x == 0) {
        if (threadIdx.x < 16) acc[threadIdx.x] = 0.0f;
        else if (threadIdx.x == 16) *ctr = 0u;
    }

    const int wave = threadIdx.x >> 6;
    const int lane = threadIdx.x & 63;
    const int wid  = blockIdx.x * 4 + wave;   // 0..2047, 4 rows per wave

    float asum = 0.0f;
    #pragma unroll
    for (int r = 0; r < 4; ++r) {
        const int idx = (wid * 4 + r) * DIM + lane;   // wave spans one row
        float u = user[idx];
        float v = item[idx];
        float su = u * u, sv = v * v;
        #pragma unroll
        for (int m = 1; m < 64; m <<= 1) {
            su += __shfl_xor(su, m, 64);
            sv += __shfl_xor(sv, m, 64);
        }
        float iu = rsqrtf(su); iu = iu * (1.5f - 0.5f * su * iu * iu);
        float iv = rsqrtf(sv); iv = iv * (1.5f - 0.5f * sv * iv * iv);
        float un = u * iu, vn = v * iv;
        xu[idx] = f32_to_bf16_rn(un * SQRT_SCALE);
        xi[idx] = f32_to_bf16_rn(vn * SQRT_SCALE);
        float d = un - vn;
        asum += d * d;
    }
    #pragma unroll
    for (int m = 1; m < 64; m <<= 1) asum += __shfl_xor(asum, m, 64);
    __shared__ float ws4[4];
    if (lane == 0) ws4[wave] = asum;
    __syncthreads();
    if (threadIdx.x == 0) pa[blockIdx.x] = ws4[0] + ws4[1] + ws4[2] + ws4[3];
}

// ---- kernel 2: 256x256 gram tile + exp + last-block finalize ---------------
// B-stripe fragment-order LDS layout per 16-row tile: ushort idx =
//   tile*1024 + c*128 + r16*8  (c = k/8 in 0..7; 2 KB per tile, 32 KB total).
// Operand read for (tile, ks): ds_read_b128 at tile*1024 + ks*512 + lane*8
//   -> contiguous 1 KB per wave, conflict-free.
__global__ void __launch_bounds__(512, 8) gram_exp_kernel(
    const unsigned short* __restrict__ xu,
    const unsigned short* __restrict__ xi,
    const float* __restrict__ pa,
    float* __restrict__ acc, unsigned* __restrict__ ctr,
    float* __restrict__ out)
{
    const int bx = blockIdx.x, by = blockIdx.y;
    const unsigned short* __restrict__ X;
    int bi, bj;
    bool is_item;
    if (by < NT2) {
        if (by >= bx) { X = xu; bi = bx; bj = by; is_item = false; }
        else          { X = xi; bi = by; bj = bx; is_item = true;  }
    } else            { X = xi; bi = bx; bj = bx; is_item = true;  }
    const bool diag = (bi == bj);

    __shared__ unsigned short lds[16384];      // 32 KB: B-stripe only
    __shared__ float wsum[8];
    __shared__ float fin[16];
    __shared__ bool amLast;

    const int wave = threadIdx.x >> 6;
    const int lane = threadIdx.x & 63;

    // A fragments straight from global (issued early, overlap staging).
    bf16x8 a[2][2];
    {
        const int arow = bi * 256 + wave * 32 + (lane & 15);
        const int acol = (lane >> 4) * 8;
        #pragma unroll
        for (int rb = 0; rb < 2; ++rb)
            #pragma unroll
            for (int ks = 0; ks < 2; ++ks)
                a[rb][ks] = *reinterpret_cast<const bf16x8*>(
                    X + (arow + rb * 16) * DIM + acol + ks * 32);
    }

    // Stage B-stripe (rows bj*256..+256), coalesced global -> fragment-order LDS.
    {
        const int base = bj * 256;
        #pragma unroll
        for (int i = 0; i < 4; ++i) {
            int n = i * 512 + threadIdx.x;       // 16B-chunk id, 0..2047
            int r = n >> 3, c = n & 7;
            bf16x8 v = *reinterpret_cast<const bf16x8*>(X + (base + r) * DIM + c * 8);
            int di = (r >> 4) * 1024 + c * 128 + (r & 15) * 8;
            *reinterpret_cast<bf16x8*>(&lds[di]) = v;
        }
    }
    __syncthreads();

    float l0 = 0.0f, l1 = 0.0f;
    #pragma unroll 2
    for (int cb = 0; cb < 16; ++cb) {
        bf16x8 b0 = *reinterpret_cast<const bf16x8*>(&lds[cb * 1024 + lane * 8]);
        bf16x8 b1 = *reinterpret_cast<const bf16x8*>(&lds[cb * 1024 + 512 + lane * 8]);
        #pragma unroll
        for (int rb = 0; rb < 2; ++rb) {
            f32x4 c = {0.f, 0.f, 0.f, 0.f};
            c = __builtin_amdgcn_mfma_f32_16x16x32_bf16(a[rb][0], b0, c, 0, 0, 0);
            c = __builtin_amdgcn_mfma_f32_16x16x32_bf16(a[rb][1], b1, c, 0, 0, 0);
            // MFMA output is already S*g (inputs pre-scaled). exp2 directly;
            // clamp at e^4 (== g<=1) only where quantization can push g>1.
            #pragma unroll
            for (int e = 0; e < 4; ++e) {
                float ex = __builtin_amdgcn_exp2f(c[e]);
                if (diag) ex = fminf(ex, E4);
                if (e & 1) l1 += ex; else l0 += ex;
            }
        }
    }

    float local = l0 + l1;
    #pragma unroll
    for (int m = 1; m < 64; m <<= 1) local += __shfl_xor(local, m, 64);
    if (lane == 0) wsum[wave] = local;
    __syncthreads();
    if (threadIdx.x == 0) {
        float t = 0.f;
        #pragma unroll
        for (int w = 0; w < 8; ++w) t += wsum[w];
        t = diag ? t : 2.0f * t;
        atomicAdd(&acc[(is_item ? 8 : 0) + (bx & 7)], t);
        __threadfence();                         // release: acc before ctr
        unsigned prev = atomicAdd(ctr, 1u);
        amLast = (prev == GRAM_SLOTS - 1);
    }
    __syncthreads();

    if (amLast) {
        __threadfence();                         // acquire
        // align reduction: pa has exactly 512 entries, block has 512 threads
        float av = pa[threadIdx.x];
        #pragma unroll
        for (int m = 1; m < 64; m <<= 1) av += __shfl_xor(av, m, 64);
        if (lane == 0) wsum[wave] = av;
        if (threadIdx.x < 16)                    // coherent read of acc slots
            fin[threadIdx.x] = atomicAdd(&acc[threadIdx.x], 0.0f);
        __syncthreads();
        if (threadIdx.x == 0) {
            float A = 0.f;
            #pragma unroll
            for (int w = 0; w < 8; ++w) A += wsum[w];
            float su = 0.f, si = 0.f;
            #pragma unroll
            for (int s = 0; s < 8; ++s) { su += fin[s]; si += fin[8 + s]; }
            su *= E4_INV; si *= E4_INV;
            const float n = (float)NROWS;
            const float denom = n * (n - 1.0f);
            out[0] = A / n + 0.5f * (logf((su - n) / denom + EPS_F)
                                   + logf((si - n) / denom + EPS_F));
        }
    }
}

extern "C" void kernel_launch(void* const* d_in, const int* in_sizes, int n_in,
                              void* d_out, int out_size, void* d_ws, size_t ws_size,
                              hipStream_t stream)
{
    const float* user = (const float*)d_in[0];
    const float* item = (const float*)d_in[1];

    unsigned short* xu = (unsigned short*)d_ws;                 // 1 MB
    unsigned short* xi = xu + (size_t)NROWS * DIM;              // 1 MB
    float* pa  = (float*)(xi + (size_t)NROWS * DIM);            // 512 floats
    float* acc = pa + K1_BLOCKS;                                // 16 floats
    unsigned* ctr = (unsigned*)(acc + 16);                      // 1 uint

    normalize_align_kernel<<<K1_BLOCKS, 256, 0, stream>>>(user, item, xu, xi,
                                                          pa, acc, ctr);
    gram_exp_kernel<<<dim3(NT2, NT2 + 1), 512, 0, stream>>>(xu, xi, pa, acc,
                                                            ctr, (float*)d_out);
}

// Round 3
// 86.648 us; speedup vs baseline: 1.0199x; 1.0199x over previous
//
#include <hip/hip_runtime.h>
#include <cstdint>

// DirectAU loss: align(u,i) + 0.5*(uniform(u) + uniform(i)), T=2, GAMMA=1.
// N=8192 rows, D=64.
//   k1: normalize rows (fp32), pre-scale by sqrt(4*log2(e)), write bf16 copies
//       to ws, per-block align partial (plain store). Block 0 zeroes the
//       spread accumulator slots + hierarchical counters.
//   k2: 256x256-tile X@X^T via mfma_f32_16x16x32_bf16, FULL unroll (R2's
//       unroll-2 reverted). Pre-scaled inputs -> MFMA output is the exp2
//       argument directly; diag tiles clamp at e^4, grand total scaled by
//       e^-4 once. Fused finalize, R2 contention fixed:
//         - partial sums -> 24 slots spread 128 B apart (<=66 RMW/address,
//           distinct L2 lines; R2 had 2112 RMWs into ONE line = serialized
//           burst, the +3.8us regression),
//         - completion via per-by sub-counters (32 incr each, spread) ->
//           33-incr master (R2: 1056 incr on one address),
//         - align (pa) reduction done EARLY by the 32 item-diag blocks,
//           overlapped with gram compute; final block reads 24 scalars only.
// Floor: harness re-poisons the 256 MiB ws with 0xAA every iteration
// (~41.4us @ 81% HBM peak, in the timed path) + ~33 tiny restore dispatches
// per iteration — untouchable. Controllable = our ~10us of kernels + gaps.

#define NROWS 8192
#define DIM 64
#define NT2 32                            // 8192/256 tiles per side
#define K1_BLOCKS 512                     // 4 waves/block * 4 rows/wave

// exp(-T*||u-v||^2) = exp(4g-4) = 2^(S*g) * e^-4, S = 4*log2(e).
static constexpr float SQRT_SCALE = 2.4022448309943147f; // sqrt(4*log2(e))
static constexpr float E4        = 54.598150033144236f;  // e^4  (clamp, diag)
static constexpr float E4_INV    = 0.018315638888734179f; // e^-4
static constexpr float EPS_F = 1e-8f;

// Spread accumulator slots: slot s lives at sums[s*32] (128 B apart).
//   slots 0..7   : align partials
//   slots 8..15  : user gram partials
//   slots 16..23 : item gram partials
#define NSLOTS 26
#define SLOT_STRIDE 32

typedef __bf16 bf16x8 __attribute__((ext_vector_type(8)));
typedef float f32x4 __attribute__((ext_vector_type(4)));

__device__ __forceinline__ unsigned short f32_to_bf16_rn(float f) {
    union { float f; uint32_t u; } c; c.f = f;
    uint32_t u = c.u;
    uint32_t r = u + 0x7FFFu + ((u >> 16) & 1u);
    return (unsigned short)(r >> 16);
}

// ---- kernel 1: normalize + scale + bf16 cast + align partial + init --------
__global__ void __launch_bounds__(256) normalize_align_kernel(
    const float* __restrict__ user, const float* __restrict__ item,
    unsigned short* __restrict__ xu, unsigned short* __restrict__ xi,
    float* __restrict__ pa, float* __restrict__ sums,
    unsigned* __restrict__ ctrs, unsigned* __restrict__ master)
{
    if (blockIdx.x == 0) {
        const int t = threadIdx.x;
        if (t < NSLOTS) sums[t * SLOT_STRIDE] = 0.0f;
        else if (t >= 32 && t < 32 + NT2 + 1) ctrs[(t - 32) * SLOT_STRIDE] = 0u;
        else if (t == 70) *master = 0u;
    }

    const int wave = threadIdx.x >> 6;
    const int lane = threadIdx.x & 63;
    const int wid  = blockIdx.x * 4 + wave;   // 0..2047, 4 rows per wave

    float asum = 0.0f;
    #pragma unroll
    for (int r = 0; r < 4; ++r) {
        const int idx = (wid * 4 + r) * DIM + lane;   // wave spans one row
        float u = user[idx];
        float v = item[idx];
        float su = u * u, sv = v * v;
        #pragma unroll
        for (int m = 1; m < 64; m <<= 1) {
            su += __shfl_xor(su, m, 64);
            sv += __shfl_xor(sv, m, 64);
        }
        float iu = rsqrtf(su); iu = iu * (1.5f - 0.5f * su * iu * iu);
        float iv = rsqrtf(sv); iv = iv * (1.5f - 0.5f * sv * iv * iv);
        float un = u * iu, vn = v * iv;
        xu[idx] = f32_to_bf16_rn(un * SQRT_SCALE);
        xi[idx] = f32_to_bf16_rn(vn * SQRT_SCALE);
        float d = un - vn;
        asum += d * d;
    }
    #pragma unroll
    for (int m = 1; m < 64; m <<= 1) asum += __shfl_xor(asum, m, 64);
    __shared__ float ws4[4];
    if (lane == 0) ws4[wave] = asum;
    __syncthreads();
    if (threadIdx.x == 0) pa[blockIdx.x] = ws4[0] + ws4[1] + ws4[2] + ws4[3];
}

// ---- kernel 2: 256x256 gram tile + exp + low-contention fused finalize -----
// B-stripe fragment-order LDS layout per 16-row tile: ushort idx =
//   tile*1024 + c*128 + r16*8  (c = k/8 in 0..7; 2 KB per tile, 32 KB total).
// Operand read for (tile, ks): ds_read_b128 at tile*1024 + ks*512 + lane*8
//   -> contiguous 1 KB per wave, conflict-free.
__global__ void __launch_bounds__(512, 8) gram_exp_kernel(
    const unsigned short* __restrict__ xu,
    const unsigned short* __restrict__ xi,
    const float* __restrict__ pa,
    float* __restrict__ sums,
    unsigned* __restrict__ ctrs, unsigned* __restrict__ master,
    float* __restrict__ out)
{
    const int bx = blockIdx.x, by = blockIdx.y;
    const unsigned short* __restrict__ X;
    int bi, bj;
    bool is_item;
    if (by < NT2) {
        if (by >= bx) { X = xu; bi = bx; bj = by; is_item = false; }
        else          { X = xi; bi = by; bj = bx; is_item = true;  }
    } else            { X = xi; bi = bx; bj = bx; is_item = true;  }
    const bool diag = (bi == bj);

    __shared__ unsigned short lds[16384];      // 32 KB: B-stripe only
    __shared__ float wsum[8];
    __shared__ float fin[NSLOTS];
    __shared__ bool amLast;

    const int wave = threadIdx.x >> 6;
    const int lane = threadIdx.x & 63;

    // A fragments straight from global (issued early, overlap staging).
    bf16x8 a[2][2];
    {
        const int arow = bi * 256 + wave * 32 + (lane & 15);
        const int acol = (lane >> 4) * 8;
        #pragma unroll
        for (int rb = 0; rb < 2; ++rb)
            #pragma unroll
            for (int ks = 0; ks < 2; ++ks)
                a[rb][ks] = *reinterpret_cast<const bf16x8*>(
                    X + (arow + rb * 16) * DIM + acol + ks * 32);
    }

    // Stage B-stripe (rows bj*256..+256), coalesced global -> fragment-order LDS.
    {
        const int base = bj * 256;
        #pragma unroll
        for (int i = 0; i < 4; ++i) {
            int n = i * 512 + threadIdx.x;       // 16B-chunk id, 0..2047
            int r = n >> 3, c = n & 7;
            bf16x8 v = *reinterpret_cast<const bf16x8*>(X + (base + r) * DIM + c * 8);
            int di = (r >> 4) * 1024 + c * 128 + (r & 15) * 8;
            *reinterpret_cast<bf16x8*>(&lds[di]) = v;
        }
    }

    // Item-diag blocks reduce the align partials early (pa ready: k1 done).
    // 32 blocks x 16 entries covers pa[0..511] exactly once; atomic overlaps
    // the gram loop below (fire-and-forget, spread slots).
    if (by == NT2 && wave == 0) {
        float s = (lane < 16) ? pa[bx * 16 + lane] : 0.0f;
        #pragma unroll
        for (int m = 1; m < 16; m <<= 1) s += __shfl_xor(s, m, 16);
        if (lane == 0) atomicAdd(&sums[(bx & 7) * SLOT_STRIDE], s);
    }
    __syncthreads();

    float l0 = 0.0f, l1 = 0.0f;
    #pragma unroll
    for (int cb = 0; cb < 16; ++cb) {
        bf16x8 b0 = *reinterpret_cast<const bf16x8*>(&lds[cb * 1024 + lane * 8]);
        bf16x8 b1 = *reinterpret_cast<const bf16x8*>(&lds[cb * 1024 + 512 + lane * 8]);
        #pragma unroll
        for (int rb = 0; rb < 2; ++rb) {
            f32x4 c = {0.f, 0.f, 0.f, 0.f};
            c = __builtin_amdgcn_mfma_f32_16x16x32_bf16(a[rb][0], b0, c, 0, 0, 0);
            c = __builtin_amdgcn_mfma_f32_16x16x32_bf16(a[rb][1], b1, c, 0, 0, 0);
            // MFMA output is already S*g (inputs pre-scaled). exp2 directly;
            // clamp at e^4 (== g<=1) only where quantization can push g>1.
            #pragma unroll
            for (int e = 0; e < 4; ++e) {
                float ex = __builtin_amdgcn_exp2f(c[e]);
                if (diag) ex = fminf(ex, E4);
                if (e & 1) l1 += ex; else l0 += ex;
            }
        }
    }

    float local = l0 + l1;
    #pragma unroll
    for (int m = 1; m < 64; m <<= 1) local += __shfl_xor(local, m, 64);
    if (lane == 0) wsum[wave] = local;
    __syncthreads();
    if (threadIdx.x == 0) {
        float t = 0.f;
        #pragma unroll
        for (int w = 0; w < 8; ++w) t += wsum[w];
        t = diag ? t : 2.0f * t;
        atomicAdd(&sums[(8 + (is_item ? 8 : 0) + (bx & 7)) * SLOT_STRIDE], t);
        __threadfence();                         // release: sums before ctr
        unsigned prev = atomicAdd(&ctrs[by * SLOT_STRIDE], 1u);
        bool last = false;
        if (prev == NT2 - 1) {                   // group of 32 complete
            __threadfence();                     // order ctr before master
            unsigned p2 = atomicAdd(master, 1u);
            last = (p2 == NT2);                  // 33rd group closer
        }
        amLast = last;
    }
    __syncthreads();

    if (amLast) {
        __threadfence();                         // acquire
        if (threadIdx.x < NSLOTS)                // coherent read of slots
            fin[threadIdx.x] = atomicAdd(&sums[threadIdx.x * SLOT_STRIDE], 0.0f);
        __syncthreads();
        if (threadIdx.x == 0) {
            float A = 0.f, su = 0.f, si = 0.f;
            #pragma unroll
            for (int s = 0; s < 8; ++s) {
                A  += fin[s];
                su += fin[8 + s];
                si += fin[16 + s];
            }
            su *= E4_INV; si *= E4_INV;
            const float n = (float)NROWS;
            const float denom = n * (n - 1.0f);
            out[0] = A / n + 0.5f * (logf((su - n) / denom + EPS_F)
                                   + logf((si - n) / denom + EPS_F));
        }
    }
}

extern "C" void kernel_launch(void* const* d_in, const int* in_sizes, int n_in,
                              void* d_out, int out_size, void* d_ws, size_t ws_size,
                              hipStream_t stream)
{
    const float* user = (const float*)d_in[0];
    const float* item = (const float*)d_in[1];

    unsigned short* xu = (unsigned short*)d_ws;                 // 1 MB
    unsigned short* xi = xu + (size_t)NROWS * DIM;              // 1 MB
    float* pa   = (float*)(xi + (size_t)NROWS * DIM);           // 512 floats
    float* sums = pa + K1_BLOCKS;                               // 26*32 floats
    unsigned* ctrs   = (unsigned*)(sums + NSLOTS * SLOT_STRIDE);// 33*32 uints
    unsigned* master = ctrs + (NT2 + 1) * SLOT_STRIDE;          // 1 uint

    normalize_align_kernel<<<K1_BLOCKS, 256, 0, stream>>>(user, item, xu, xi,
                                                          pa, sums, ctrs, master);
    gram_exp_kernel<<<dim3(NT2, NT2 + 1), 512, 0, stream>>>(xu, xi, pa, sums,
                                                            ctrs, master,
                                                            (float*)d_out);
}

// Round 4
// 82.595 us; speedup vs baseline: 1.0699x; 1.0491x over previous
//
#include <hip/hip_runtime.h>
#include <cstdint>

// DirectAU loss: align(u,i) + 0.5*(uniform(u) + uniform(i)), T=2, GAMMA=1.
// N=8192 rows, D=64.
//   k1: normalize rows (fp32), pre-scale by sqrt(4*log2(e)), write bf16 copies
//       to ws, per-block align partial.
//   k2: 256x256-tile X@X^T via mfma_f32_16x16x32_bf16. B-stripe (32 KB) staged
//       to LDS in fragment order (conflict-free ds_read_b128); A-fragments
//       read directly from global before the barrier. 4 blocks/CU -> all 1056
//       blocks co-resident. Pre-scaled inputs: MFMA output IS the exp2
//       argument (saves 128 v_fma/wave vs R0); diag tiles clamp at e^4,
//       totals scaled by e^-4 once in k3. Fused exp2+sum epilogue,
//       per-block partial to pg (plain store, no atomics).
//   k3: reduce partials + combine -> d_out[0].
// R2/R3 lesson: fusing k3 into k2 via last-block atomics/fences cost +2-4us
// (1056 device-scope fences + atomic tail > one ~2us graph-captured launch).
// Reverted to the proven R0 3-kernel structure; prescale is the only delta.
// Floor: harness re-poisons the 256 MiB ws with 0xAA every iteration
// (~41.4us @ 81% HBM peak, in the timed path) — untouchable.

#define NROWS 8192
#define DIM 64
#define NT2 32                            // 8192/256 tiles per side
#define GRAM_SLOTS (NT2 * (NT2 + 1))      // 32*33 = 1056
#define K1_BLOCKS 512                     // 4 waves/block * 4 rows/wave

// exp(-T*||u-v||^2) = exp(4g-4) = 2^(S*g) * e^-4, S = 4*log2(e).
static constexpr float SQRT_SCALE = 2.4022448309943147f; // sqrt(4*log2(e))
static constexpr float E4        = 54.598150033144236f;  // e^4  (clamp, diag)
static constexpr float E4_INV    = 0.018315638888734179f; // e^-4
static constexpr float EPS_F = 1e-8f;

typedef __bf16 bf16x8 __attribute__((ext_vector_type(8)));
typedef float f32x4 __attribute__((ext_vector_type(4)));

__device__ __forceinline__ unsigned short f32_to_bf16_rn(float f) {
    union { float f; uint32_t u; } c; c.f = f;
    uint32_t u = c.u;
    uint32_t r = u + 0x7FFFu + ((u >> 16) & 1u);
    return (unsigned short)(r >> 16);
}

// ---- kernel 1: normalize + scale + bf16 cast + per-block align partial -----
__global__ void __launch_bounds__(256) normalize_align_kernel(
    const float* __restrict__ user, const float* __restrict__ item,
    unsigned short* __restrict__ xu, unsigned short* __restrict__ xi,
    float* __restrict__ pa)
{
    const int wave = threadIdx.x >> 6;
    const int lane = threadIdx.x & 63;
    const int wid  = blockIdx.x * 4 + wave;   // 0..2047, 4 rows per wave

    float asum = 0.0f;
    #pragma unroll
    for (int r = 0; r < 4; ++r) {
        const int idx = (wid * 4 + r) * DIM + lane;   // wave spans one row
        float u = user[idx];
        float v = item[idx];
        float su = u * u, sv = v * v;
        #pragma unroll
        for (int m = 1; m < 64; m <<= 1) {
            su += __shfl_xor(su, m, 64);
            sv += __shfl_xor(sv, m, 64);
        }
        float iu = rsqrtf(su); iu = iu * (1.5f - 0.5f * su * iu * iu);
        float iv = rsqrtf(sv); iv = iv * (1.5f - 0.5f * sv * iv * iv);
        float un = u * iu, vn = v * iv;
        xu[idx] = f32_to_bf16_rn(un * SQRT_SCALE);
        xi[idx] = f32_to_bf16_rn(vn * SQRT_SCALE);
        float d = un - vn;
        asum += d * d;
    }
    #pragma unroll
    for (int m = 1; m < 64; m <<= 1) asum += __shfl_xor(asum, m, 64);
    __shared__ float ws4[4];
    if (lane == 0) ws4[wave] = asum;
    __syncthreads();
    if (threadIdx.x == 0) pa[blockIdx.x] = ws4[0] + ws4[1] + ws4[2] + ws4[3];
}

// ---- kernel 2: 256x256 gram tile + exp + per-block partial -----------------
// B-stripe fragment-order LDS layout per 16-row tile: ushort idx =
//   tile*1024 + c*128 + r16*8  (c = k/8 in 0..7; 2 KB per tile, 32 KB total).
// Operand read for (tile, ks): ds_read_b128 at tile*1024 + ks*512 + lane*8
//   -> contiguous 1 KB per wave, conflict-free (same addr across waves).
__global__ void __launch_bounds__(512, 8) gram_exp_kernel(
    const unsigned short* __restrict__ xu,
    const unsigned short* __restrict__ xi,
    float* __restrict__ pg)
{
    const int bx = blockIdx.x, by = blockIdx.y;
    const unsigned short* __restrict__ X;
    int bi, bj;
    if (by < NT2) {
        if (by >= bx) { X = xu; bi = bx; bj = by; }
        else          { X = xi; bi = by; bj = bx; }
    } else            { X = xi; bi = bx; bj = bx; }
    const bool diag = (bi == bj);

    __shared__ unsigned short lds[16384];      // 32 KB: B-stripe only
    __shared__ float wsum[8];

    const int wave = threadIdx.x >> 6;
    const int lane = threadIdx.x & 63;

    // A fragments straight from global (issued early, overlap staging).
    // rows bi*256 + wave*32 + rb*16 + (lane&15); 16B-aligned bf16x8 chunks.
    bf16x8 a[2][2];
    {
        const int arow = bi * 256 + wave * 32 + (lane & 15);
        const int acol = (lane >> 4) * 8;
        #pragma unroll
        for (int rb = 0; rb < 2; ++rb)
            #pragma unroll
            for (int ks = 0; ks < 2; ++ks)
                a[rb][ks] = *reinterpret_cast<const bf16x8*>(
                    X + (arow + rb * 16) * DIM + acol + ks * 32);
    }

    // Stage B-stripe (rows bj*256..+256), coalesced global -> fragment-order LDS.
    {
        const int base = bj * 256;
        #pragma unroll
        for (int i = 0; i < 4; ++i) {
            int n = i * 512 + threadIdx.x;       // 16B-chunk id, 0..2047
            int r = n >> 3, c = n & 7;
            bf16x8 v = *reinterpret_cast<const bf16x8*>(X + (base + r) * DIM + c * 8);
            int di = (r >> 4) * 1024 + c * 128 + (r & 15) * 8;
            *reinterpret_cast<bf16x8*>(&lds[di]) = v;
        }
    }
    __syncthreads();

    float l0 = 0.0f, l1 = 0.0f;
    #pragma unroll
    for (int cb = 0; cb < 16; ++cb) {
        bf16x8 b0 = *reinterpret_cast<const bf16x8*>(&lds[cb * 1024 + lane * 8]);
        bf16x8 b1 = *reinterpret_cast<const bf16x8*>(&lds[cb * 1024 + 512 + lane * 8]);
        #pragma unroll
        for (int rb = 0; rb < 2; ++rb) {
            f32x4 c = {0.f, 0.f, 0.f, 0.f};
            c = __builtin_amdgcn_mfma_f32_16x16x32_bf16(a[rb][0], b0, c, 0, 0, 0);
            c = __builtin_amdgcn_mfma_f32_16x16x32_bf16(a[rb][1], b1, c, 0, 0, 0);
            // Inputs pre-scaled: c[e] = S*g already. exp(-T*max(2-2g,0))
            // = 2^(S*g) * e^-4, clamped at e^4 (g<=1) on diag tiles only.
            #pragma unroll
            for (int e = 0; e < 4; ++e) {
                float ex = __builtin_amdgcn_exp2f(c[e]);
                if (diag) ex = fminf(ex, E4);
                if (e & 1) l1 += ex; else l0 += ex;
            }
        }
    }

    float local = l0 + l1;
    #pragma unroll
    for (int m = 1; m < 64; m <<= 1) local += __shfl_xor(local, m, 64);
    if (lane == 0) wsum[wave] = local;
    __syncthreads();
    if (threadIdx.x == 0) {
        float t = 0.f;
        #pragma unroll
        for (int w = 0; w < 8; ++w) t += wsum[w];
        pg[by * NT2 + bx] = diag ? t : 2.0f * t;
    }
}

// ---- kernel 3: reduce partials + combine -----------------------------------
__global__ void __launch_bounds__(256) final_kernel(
    const float* __restrict__ pa, const float* __restrict__ pg,
    float* __restrict__ out)
{
    float a = 0.f, su = 0.f, si = 0.f;
    for (int s = threadIdx.x; s < K1_BLOCKS; s += 256) a += pa[s];
    for (int s = threadIdx.x; s < GRAM_SLOTS; s += 256) {
        int bx = s & (NT2 - 1), by = s >> 5;
        bool is_item = (by == NT2) || (by < bx);
        float v = pg[s];
        if (is_item) si += v; else su += v;
    }
    #pragma unroll
    for (int m = 1; m < 64; m <<= 1) {
        a  += __shfl_xor(a,  m, 64);
        su += __shfl_xor(su, m, 64);
        si += __shfl_xor(si, m, 64);
    }
    __shared__ float r[12];
    const int wave = threadIdx.x >> 6, lane = threadIdx.x & 63;
    if (lane == 0) { r[wave] = a; r[4 + wave] = su; r[8 + wave] = si; }
    __syncthreads();
    if (threadIdx.x == 0) {
        float A  = r[0] + r[1] + r[2]  + r[3];
        float SU = (r[4] + r[5] + r[6]  + r[7])  * E4_INV;
        float SI = (r[8] + r[9] + r[10] + r[11]) * E4_INV;
        const float n = (float)NROWS;
        const float denom = n * (n - 1.0f);
        out[0] = A / n + 0.5f * (logf((SU - n) / denom + EPS_F)
                               + logf((SI - n) / denom + EPS_F));
    }
}

extern "C" void kernel_launch(void* const* d_in, const int* in_sizes, int n_in,
                              void* d_out, int out_size, void* d_ws, size_t ws_size,
                              hipStream_t stream)
{
    const float* user = (const float*)d_in[0];
    const float* item = (const float*)d_in[1];

    unsigned short* xu = (unsigned short*)d_ws;                 // 1 MB
    unsigned short* xi = xu + (size_t)NROWS * DIM;              // 1 MB
    float* pa = (float*)(xi + (size_t)NROWS * DIM);             // 512 floats
    float* pg = pa + K1_BLOCKS;                                 // 1056 floats

    normalize_align_kernel<<<K1_BLOCKS, 256, 0, stream>>>(user, item, xu, xi, pa);
    gram_exp_kernel<<<dim3(NT2, NT2 + 1), 512, 0, stream>>>(xu, xi, pg);
    final_kernel<<<1, 256, 0, stream>>>(pa, pg, (float*)d_out);
}

// Round 6
// 76.339 us; speedup vs baseline: 1.1576x; 1.0820x over previous
//
#include <hip/hip_runtime.h>
#include <cstdint>
#include <type_traits>

// DirectAU loss: align(u,i) + 0.5*(uniform(u) + uniform(i)), T=2, GAMMA=1.
// N=8192 rows, D=64.
//   k1: normalize rows (fp32), pre-scale by sqrt(4*log2(e)), write bf16 copies
//       to ws, per-block align partial.
//   k2: 256x256-tile X@X^T via mfma_f32_16x16x32_bf16. B-stripe (32 KB) staged
//       to LDS in fragment order (conflict-free ds_read_b128); A-fragments
//       read directly from global before the barrier. 4 blocks/CU. Pre-scaled
//       inputs: MFMA output IS the exp2 argument. k2 is VALU-bound (exp2 is
//       the floor at ~3.5us chip-wide); R5 trims the VALU around it:
//         - persistent zero-quad as C of the first MFMA (D!=C in the ISA;
//           kills 8 v_mov zero-inits per cb iter),
//         - f32x2 packed accumulators -> v_pk_add_f32 (halves add cost),
//         - diag clamp branch-hoisted via if constexpr loop duplication
//           (uniform branch; non-diag blocks carry zero clamp cost).
//   k3: reduce partials + combine -> d_out[0].
// R2/R3 lesson: last-block fusion with device-scope fences cost +2-4us; dead.
// R5 note: bench died in container acquire (no kernel signal), same as R1.
// Audit found nothing container-killing (only reassociation + uniform-branch
// duplication vs the passing R4 kernel); resubmitting unchanged.
// Floor: harness re-poisons the 256 MiB ws with 0xAA every iteration
// (~41.4us @ 81% HBM peak, in the timed path) + ~30us of tiny restore
// dispatches — untouchable. Controllable = our ~8-10us of kernels.

#define NROWS 8192
#define DIM 64
#define NT2 32                            // 8192/256 tiles per side
#define GRAM_SLOTS (NT2 * (NT2 + 1))      // 32*33 = 1056
#define K1_BLOCKS 512                     // 4 waves/block * 4 rows/wave

// exp(-T*||u-v||^2) = exp(4g-4) = 2^(S*g) * e^-4, S = 4*log2(e).
static constexpr float SQRT_SCALE = 2.4022448309943147f; // sqrt(4*log2(e))
static constexpr float E4        = 54.598150033144236f;  // e^4  (clamp, diag)
static constexpr float E4_INV    = 0.018315638888734179f; // e^-4
static constexpr float EPS_F = 1e-8f;

typedef __bf16 bf16x8 __attribute__((ext_vector_type(8)));
typedef float f32x4 __attribute__((ext_vector_type(4)));
typedef float f32x2 __attribute__((ext_vector_type(2)));

__device__ __forceinline__ unsigned short f32_to_bf16_rn(float f) {
    union { float f; uint32_t u; } c; c.f = f;
    uint32_t u = c.u;
    uint32_t r = u + 0x7FFFu + ((u >> 16) & 1u);
    return (unsigned short)(r >> 16);
}

// ---- kernel 1: normalize + scale + bf16 cast + per-block align partial -----
__global__ void __launch_bounds__(256) normalize_align_kernel(
    const float* __restrict__ user, const float* __restrict__ item,
    unsigned short* __restrict__ xu, unsigned short* __restrict__ xi,
    float* __restrict__ pa)
{
    const int wave = threadIdx.x >> 6;
    const int lane = threadIdx.x & 63;
    const int wid  = blockIdx.x * 4 + wave;   // 0..2047, 4 rows per wave

    float asum = 0.0f;
    #pragma unroll
    for (int r = 0; r < 4; ++r) {
        const int idx = (wid * 4 + r) * DIM + lane;   // wave spans one row
        float u = user[idx];
        float v = item[idx];
        float su = u * u, sv = v * v;
        #pragma unroll
        for (int m = 1; m < 64; m <<= 1) {
            su += __shfl_xor(su, m, 64);
            sv += __shfl_xor(sv, m, 64);
        }
        float iu = rsqrtf(su); iu = iu * (1.5f - 0.5f * su * iu * iu);
        float iv = rsqrtf(sv); iv = iv * (1.5f - 0.5f * sv * iv * iv);
        float un = u * iu, vn = v * iv;
        xu[idx] = f32_to_bf16_rn(un * SQRT_SCALE);
        xi[idx] = f32_to_bf16_rn(vn * SQRT_SCALE);
        float d = un - vn;
        asum += d * d;
    }
    #pragma unroll
    for (int m = 1; m < 64; m <<= 1) asum += __shfl_xor(asum, m, 64);
    __shared__ float ws4[4];
    if (lane == 0) ws4[wave] = asum;
    __syncthreads();
    if (threadIdx.x == 0) pa[blockIdx.x] = ws4[0] + ws4[1] + ws4[2] + ws4[3];
}

// ---- kernel 2: 256x256 gram tile + exp + per-block partial -----------------
// B-stripe fragment-order LDS layout per 16-row tile: ushort idx =
//   tile*1024 + c*128 + r16*8  (c = k/8 in 0..7; 2 KB per tile, 32 KB total).
// Operand read for (tile, ks): ds_read_b128 at tile*1024 + ks*512 + lane*8
//   -> contiguous 1 KB per wave, conflict-free (same addr across waves).
__global__ void __launch_bounds__(512, 8) gram_exp_kernel(
    const unsigned short* __restrict__ xu,
    const unsigned short* __restrict__ xi,
    float* __restrict__ pg)
{
    const int bx = blockIdx.x, by = blockIdx.y;
    const unsigned short* __restrict__ X;
    int bi, bj;
    if (by < NT2) {
        if (by >= bx) { X = xu; bi = bx; bj = by; }
        else          { X = xi; bi = by; bj = bx; }
    } else            { X = xi; bi = bx; bj = bx; }
    const bool diag = (bi == bj);

    __shared__ unsigned short lds[16384];      // 32 KB: B-stripe only
    __shared__ float wsum[8];

    const int wave = threadIdx.x >> 6;
    const int lane = threadIdx.x & 63;

    // A fragments straight from global (issued early, overlap staging).
    // rows bi*256 + wave*32 + rb*16 + (lane&15); 16B-aligned bf16x8 chunks.
    bf16x8 a[2][2];
    {
        const int arow = bi * 256 + wave * 32 + (lane & 15);
        const int acol = (lane >> 4) * 8;
        #pragma unroll
        for (int rb = 0; rb < 2; ++rb)
            #pragma unroll
            for (int ks = 0; ks < 2; ++ks)
                a[rb][ks] = *reinterpret_cast<const bf16x8*>(
                    X + (arow + rb * 16) * DIM + acol + ks * 32);
    }

    // Stage B-stripe (rows bj*256..+256), coalesced global -> fragment-order LDS.
    {
        const int base = bj * 256;
        #pragma unroll
        for (int i = 0; i < 4; ++i) {
            int n = i * 512 + threadIdx.x;       // 16B-chunk id, 0..2047
            int r = n >> 3, c = n & 7;
            bf16x8 v = *reinterpret_cast<const bf16x8*>(X + (base + r) * DIM + c * 8);
            int di = (r >> 4) * 1024 + c * 128 + (r & 15) * 8;
            *reinterpret_cast<bf16x8*>(&lds[di]) = v;
        }
    }
    __syncthreads();

    const f32x4 ZQ = {0.f, 0.f, 0.f, 0.f};     // persistent zero C-operand
    f32x2 acc0 = {0.f, 0.f}, acc1 = {0.f, 0.f};

    auto gram_loop = [&](auto dgc) {
        #pragma unroll
        for (int cb = 0; cb < 16; ++cb) {
            bf16x8 b0 = *reinterpret_cast<const bf16x8*>(&lds[cb * 1024 + lane * 8]);
            bf16x8 b1 = *reinterpret_cast<const bf16x8*>(&lds[cb * 1024 + 512 + lane * 8]);
            #pragma unroll
            for (int rb = 0; rb < 2; ++rb) {
                // D != C in the MFMA ISA: first MFMA reads the hoisted zero
                // quad, no per-iter v_mov zero-init.
                f32x4 c = __builtin_amdgcn_mfma_f32_16x16x32_bf16(a[rb][0], b0, ZQ, 0, 0, 0);
                c = __builtin_amdgcn_mfma_f32_16x16x32_bf16(a[rb][1], b1, c, 0, 0, 0);
                // Inputs pre-scaled: c[e] = S*g. exp(-T*max(2-2g,0))
                // = 2^(S*g) * e^-4, clamped at e^4 (g<=1) on diag tiles only.
                float e0 = __builtin_amdgcn_exp2f(c[0]);
                float e1 = __builtin_amdgcn_exp2f(c[1]);
                float e2 = __builtin_amdgcn_exp2f(c[2]);
                float e3 = __builtin_amdgcn_exp2f(c[3]);
                if constexpr (decltype(dgc)::value) {
                    e0 = fminf(e0, E4); e1 = fminf(e1, E4);
                    e2 = fminf(e2, E4); e3 = fminf(e3, E4);
                }
                f32x2 p0 = {e0, e1}, p1 = {e2, e3};
                acc0 += p0;                       // v_pk_add_f32
                acc1 += p1;
            }
        }
    };
    if (diag) gram_loop(std::true_type{});
    else      gram_loop(std::false_type{});

    float local = acc0[0] + acc0[1] + acc1[0] + acc1[1];
    #pragma unroll
    for (int m = 1; m < 64; m <<= 1) local += __shfl_xor(local, m, 64);
    if (lane == 0) wsum[wave] = local;
    __syncthreads();
    if (threadIdx.x == 0) {
        float t = 0.f;
        #pragma unroll
        for (int w = 0; w < 8; ++w) t += wsum[w];
        pg[by * NT2 + bx] = diag ? t : 2.0f * t;
    }
}

// ---- kernel 3: reduce partials + combine -----------------------------------
__global__ void __launch_bounds__(256) final_kernel(
    const float* __restrict__ pa, const float* __restrict__ pg,
    float* __restrict__ out)
{
    float a = 0.f, su = 0.f, si = 0.f;
    for (int s = threadIdx.x; s < K1_BLOCKS; s += 256) a += pa[s];
    for (int s = threadIdx.x; s < GRAM_SLOTS; s += 256) {
        int bx = s & (NT2 - 1), by = s >> 5;
        bool is_item = (by == NT2) || (by < bx);
        float v = pg[s];
        if (is_item) si += v; else su += v;
    }
    #pragma unroll
    for (int m = 1; m < 64; m <<= 1) {
        a  += __shfl_xor(a,  m, 64);
        su += __shfl_xor(su, m, 64);
        si += __shfl_xor(si, m, 64);
    }
    __shared__ float r[12];
    const int wave = threadIdx.x >> 6, lane = threadIdx.x & 63;
    if (lane == 0) { r[wave] = a; r[4 + wave] = su; r[8 + wave] = si; }
    __syncthreads();
    if (threadIdx.x == 0) {
        float A  = r[0] + r[1] + r[2]  + r[3];
        float SU = (r[4] + r[5] + r[6]  + r[7])  * E4_INV;
        float SI = (r[8] + r[9] + r[10] + r[11]) * E4_INV;
        const float n = (float)NROWS;
        const float denom = n * (n - 1.0f);
        out[0] = A / n + 0.5f * (logf((SU - n) / denom + EPS_F)
                               + logf((SI - n) / denom + EPS_F));
    }
}

extern "C" void kernel_launch(void* const* d_in, const int* in_sizes, int n_in,
                              void* d_out, int out_size, void* d_ws, size_t ws_size,
                              hipStream_t stream)
{
    const float* user = (const float*)d_in[0];
    const float* item = (const float*)d_in[1];

    unsigned short* xu = (unsigned short*)d_ws;                 // 1 MB
    unsigned short* xi = xu + (size_t)NROWS * DIM;              // 1 MB
    float* pa = (float*)(xi + (size_t)NROWS * DIM);             // 512 floats
    float* pg = pa + K1_BLOCKS;                                 // 1056 floats

    normalize_align_kernel<<<K1_BLOCKS, 256, 0, stream>>>(user, item, xu, xi, pa);
    gram_exp_kernel<<<dim3(NT2, NT2 + 1), 512, 0, stream>>>(xu, xi, pg);
    final_kernel<<<1, 256, 0, stream>>>(pa, pg, (float*)d_out);
}